// Round 2
// baseline (412.641 us; speedup 1.0000x reference)
//
#include <hip/hip_runtime.h>

#define TPB 256

// Problem dims
constexpr int B_ = 4096, A_ = 11, D_ = 256;
constexpr int R_ = B_ * A_;       // 45056 rows
constexpr int K32 = 32;           // L*IN folded input dim

// ws offsets (in floats)
constexpr int WC_O   = 0;          // 4*256   W_in @ W_pos_top
constexpr int XB_O   = 1024;       // 8*256   per-timestep bias (pe etc.)
constexpr int M_O    = 3072;       // 32*256  folded through fc2
constexpr int CB_O   = 11264;      // 256     folded bias through fc2
constexpr int M2_O   = 11520;      // 32*256  folded through fc3
constexpr int B2_O   = 19712;      // 11*256  per-agent bias (ftraj)
constexpr int WN2L_O = 22528;      // 64*64   Wn2 @ W_line
constexpr int MH1_O  = 26624;      // 32*64   M2 @ Wh1
constexpr int BH1_O  = 28672;      // 11*64
constexpr int MH2_O  = 29376;      // 32*64   M2 @ Wh2
constexpr int BH2_O  = 31424;      // 11*64
constexpr int U1_O   = 32768;      // also reused as AGG1 after k_scene2
constexpr int SZ_RH  = R_ * 64;    // 2883584
constexpr int V1_O   = U1_O + SZ_RH;
constexpr int U2_O   = V1_O + SZ_RH;   // also reused as AGG2
constexpr int V2_O   = U2_O + SZ_RH;

// ---------------- precompute: fold weight chains ----------------

__global__ __launch_bounds__(TPB) void k_pre1(const float* __restrict__ Win,
                                              const float* __restrict__ bin,
                                              const float* __restrict__ Wpos,
                                              const float* __restrict__ bpos,
                                              float* __restrict__ ws) {
    int idx = blockIdx.x * TPB + threadIdx.x;   // grid 12 -> 3072
    if (idx < 1024) {                           // Wc[i][j] = sum_d Win[i][d]*Wpos[d][j]
        int i = idx >> 8, j = idx & 255;
        float acc = 0.f;
        for (int d = 0; d < 256; ++d) acc += Win[i*256+d] * Wpos[d*256+j];
        ws[WC_O + idx] = acc;
    } else {                                    // xb[l][j] = b_in@Wpos_top + pe[l]@Wpos_bot + bpos
        int o = idx - 1024;                     // < 2048
        int l = o >> 8, j = o & 255;
        float acc = bpos[j];
        for (int d = 0; d < 256; ++d) acc += bin[d] * Wpos[d*256+j];
        const float c0 = -logf(10000.f) / 256.f;
        for (int i = 0; i < 128; ++i) {
            float freq = expf((float)(2*i) * c0);
            float ang = (float)l * freq;
            acc += sinf(ang) * Wpos[(256 + 2*i)*256 + j];
            acc += cosf(ang) * Wpos[(256 + 2*i + 1)*256 + j];
        }
        ws[XB_O + o] = acc;
    }
}

__global__ __launch_bounds__(TPB) void k_pre2(const float* __restrict__ Wfc2,
                                              const float* __restrict__ bfc2,
                                              float* __restrict__ ws) {
    if (blockIdx.x < 32) {
        int idx = blockIdx.x * TPB + threadIdx.x;  // < 8192
        int k = idx >> 8, j = idx & 255;
        int l = k >> 2, i = k & 3;
        float acc = 0.f;
        for (int d = 0; d < 256; ++d)
            acc += ws[WC_O + i*256 + d] * Wfc2[l*65536 + d*256 + j];
        ws[M_O + idx] = acc;
    } else {
        int j = threadIdx.x;
        float acc = bfc2[j];
        for (int l = 0; l < 8; ++l)
            for (int d = 0; d < 256; ++d)
                acc += ws[XB_O + l*256 + d] * Wfc2[l*65536 + d*256 + j];
        ws[CB_O + j] = acc;
    }
}

__global__ __launch_bounds__(TPB) void k_pre3(const float* __restrict__ Wfc3,
                                              const float* __restrict__ bfc3,
                                              const float* __restrict__ Wn2,
                                              const float* __restrict__ Wline,
                                              float* __restrict__ ws) {
    int idx = blockIdx.x * TPB + threadIdx.x;   // grid 59 -> 15104
    if (idx < 8192) {                           // M2 = M @ Wfc3_top
        int k = idx >> 8, j = idx & 255;
        float acc = 0.f;
        for (int d = 0; d < 256; ++d) acc += ws[M_O + k*256 + d] * Wfc3[d*256 + j];
        ws[M2_O + idx] = acc;
    } else if (idx < 11008) {                   // bias2[a] = cb@Wfc3_top + Wfc3[256+a] + bfc3
        int o = idx - 8192;
        int a = o >> 8, j = o & 255;
        float acc = bfc3[j] + Wfc3[(256 + a)*256 + j];
        for (int d = 0; d < 256; ++d) acc += ws[CB_O + d] * Wfc3[d*256 + j];
        ws[B2_O + o] = acc;
    } else if (idx < 15104) {                   // Wn2L = Wn2 @ W_line
        int o = idx - 11008;
        int k = o >> 6, c = o & 63;
        float acc = 0.f;
        for (int d = 0; d < 256; ++d) acc += Wn2[k*256 + d] * Wline[d*64 + c];
        ws[WN2L_O + o] = acc;
    }
}

__global__ __launch_bounds__(TPB) void k_pre4(const float* __restrict__ Wh1,
                                              const float* __restrict__ Wh2,
                                              float* __restrict__ ws) {
    int idx = blockIdx.x * TPB + threadIdx.x;   // grid 22 -> 5632, valid < 5504
    if (idx < 2048) {                           // Mh1 = M2 @ Wh1
        int k = idx >> 6, c = idx & 63;
        float acc = 0.f;
        for (int d = 0; d < 256; ++d) acc += ws[M2_O + k*256 + d] * Wh1[d*64 + c];
        ws[MH1_O + idx] = acc;
    } else if (idx < 2752) {                    // bh1 = bias2 @ Wh1
        int o = idx - 2048;
        int a = o >> 6, c = o & 63;
        float acc = 0.f;
        for (int d = 0; d < 256; ++d) acc += ws[B2_O + a*256 + d] * Wh1[d*64 + c];
        ws[BH1_O + o] = acc;
    } else if (idx < 4800) {                    // Mh2 = M2 @ Wh2
        int o = idx - 2752;
        int k = o >> 6, c = o & 63;
        float acc = 0.f;
        for (int d = 0; d < 256; ++d) acc += ws[M2_O + k*256 + d] * Wh2[d*64 + c];
        ws[MH2_O + o] = acc;
    } else if (idx < 5504) {                    // bh2 = bias2 @ Wh2
        int o = idx - 4800;
        int a = o >> 6, c = o & 63;
        float acc = 0.f;
        for (int d = 0; d < 256; ++d) acc += ws[B2_O + a*256 + d] * Wh2[d*64 + c];
        ws[BH2_O + o] = acc;
    }
}

// ---------------- k_rows: ftraj + h1/h2 + u/v, register-tiled over 64-row blocks ----------------
// thread tile: 4 rows (tg=t>>4, r0=tg*4); ftraj cols: 16 (tc*16); h/uv cols: 4 (tc*4)
// LDS stride 68 floats: 16B-aligned b128, conflict-free reads (4 distinct 16B addrs/wave)

__global__ __launch_bounds__(TPB) void k_rows(const float* __restrict__ in,
                                              const float* __restrict__ We1g,
                                              const float* __restrict__ We2g,
                                              float* __restrict__ ws,
                                              float* __restrict__ out) {
    __shared__ float inT[32*68];
    __shared__ float hT[64*68];
    const int t = threadIdx.x;
    const int rowBase = blockIdx.x * 64;
    const int tg = t >> 4, tc = t & 15;
    const int r0 = tg * 4, c0 = tc * 4;

    // stage input transposed: inT[k][row]
    {
        int row = t >> 2, c8 = (t & 3) * 8;
        const float* src = in + (size_t)(rowBase + row) * K32 + c8;
        float4 a = *(const float4*)src;
        float4 b = *(const float4*)(src + 4);
        inT[(c8+0)*68 + row] = a.x; inT[(c8+1)*68 + row] = a.y;
        inT[(c8+2)*68 + row] = a.z; inT[(c8+3)*68 + row] = a.w;
        inT[(c8+4)*68 + row] = b.x; inT[(c8+5)*68 + row] = b.y;
        inT[(c8+6)*68 + row] = b.z; inT[(c8+7)*68 + row] = b.w;
    }
    __syncthreads();

    int ag[4];
    #pragma unroll
    for (int r = 0; r < 4; ++r) ag[r] = (rowBase + r0 + r) % 11;

    // ---- ftraj = in @ M2 + bias2[ag]  -> out[:,0:256] ----
    {
        float acc[4][16];
        #pragma unroll
        for (int r = 0; r < 4; ++r)
            #pragma unroll
            for (int c = 0; c < 16; ++c) acc[r][c] = 0.f;
        for (int k = 0; k < 32; ++k) {
            float4 av4 = *(const float4*)&inT[k*68 + r0];
            float avr[4] = {av4.x, av4.y, av4.z, av4.w};
            float4 bv[4];
            #pragma unroll
            for (int j = 0; j < 4; ++j)
                bv[j] = *(const float4*)&ws[M2_O + k*256 + tc*16 + j*4];
            #pragma unroll
            for (int r = 0; r < 4; ++r)
                #pragma unroll
                for (int j = 0; j < 4; ++j) {
                    acc[r][j*4+0] += avr[r] * bv[j].x;
                    acc[r][j*4+1] += avr[r] * bv[j].y;
                    acc[r][j*4+2] += avr[r] * bv[j].z;
                    acc[r][j*4+3] += avr[r] * bv[j].w;
                }
        }
        #pragma unroll
        for (int r = 0; r < 4; ++r) {
            size_t ob = (size_t)(rowBase + r0 + r) * 576 + tc*16;
            #pragma unroll
            for (int j = 0; j < 4; ++j) {
                float4 b = *(const float4*)&ws[B2_O + ag[r]*256 + tc*16 + j*4];
                float4 o = make_float4(acc[r][j*4+0]+b.x, acc[r][j*4+1]+b.y,
                                       acc[r][j*4+2]+b.z, acc[r][j*4+3]+b.w);
                *(float4*)&out[ob + j*4] = o;
            }
        }
    }

    // ---- two NMP stages: h = relu(in@Mh + bh), u = h@We_top, v = h@We_bot ----
    for (int s = 0; s < 2; ++s) {
        const float* Mh  = ws + (s ? MH2_O : MH1_O);
        const float* bh  = ws + (s ? BH2_O : BH1_O);
        const float* We  = s ? We2g : We1g;
        float* ug = ws + (s ? U2_O : U1_O);
        float* vg = ws + (s ? V2_O : V1_O);

        float hacc[4][4];
        #pragma unroll
        for (int r = 0; r < 4; ++r)
            #pragma unroll
            for (int c = 0; c < 4; ++c) hacc[r][c] = 0.f;
        for (int k = 0; k < 32; ++k) {
            float4 av4 = *(const float4*)&inT[k*68 + r0];
            float avr[4] = {av4.x, av4.y, av4.z, av4.w};
            float4 bv = *(const float4*)&Mh[k*64 + c0];
            #pragma unroll
            for (int r = 0; r < 4; ++r) {
                hacc[r][0] += avr[r] * bv.x; hacc[r][1] += avr[r] * bv.y;
                hacc[r][2] += avr[r] * bv.z; hacc[r][3] += avr[r] * bv.w;
            }
        }
        float hv[4][4];
        #pragma unroll
        for (int r = 0; r < 4; ++r) {
            float4 b = *(const float4*)&bh[ag[r]*64 + c0];
            hv[r][0] = fmaxf(hacc[r][0] + b.x, 0.f);
            hv[r][1] = fmaxf(hacc[r][1] + b.y, 0.f);
            hv[r][2] = fmaxf(hacc[r][2] + b.z, 0.f);
            hv[r][3] = fmaxf(hacc[r][3] + b.w, 0.f);
        }
        if (s == 1) __syncthreads();  // stage-1 hT reads done before overwrite
        #pragma unroll
        for (int c = 0; c < 4; ++c)
            *(float4*)&hT[(c0+c)*68 + r0] =
                make_float4(hv[0][c], hv[1][c], hv[2][c], hv[3][c]);
        __syncthreads();

        float ua[4][4], va[4][4];
        #pragma unroll
        for (int r = 0; r < 4; ++r)
            #pragma unroll
            for (int c = 0; c < 4; ++c) { ua[r][c] = 0.f; va[r][c] = 0.f; }
        for (int k = 0; k < 64; ++k) {
            float4 av4 = *(const float4*)&hT[k*68 + r0];
            float avr[4] = {av4.x, av4.y, av4.z, av4.w};
            float4 bu = *(const float4*)&We[k*64 + c0];
            float4 bw = *(const float4*)&We[(k+64)*64 + c0];
            #pragma unroll
            for (int r = 0; r < 4; ++r) {
                ua[r][0] += avr[r] * bu.x; ua[r][1] += avr[r] * bu.y;
                ua[r][2] += avr[r] * bu.z; ua[r][3] += avr[r] * bu.w;
                va[r][0] += avr[r] * bw.x; va[r][1] += avr[r] * bw.y;
                va[r][2] += avr[r] * bw.z; va[r][3] += avr[r] * bw.w;
            }
        }
        #pragma unroll
        for (int r = 0; r < 4; ++r) {
            size_t rb = (size_t)(rowBase + r0 + r) * 64 + c0;
            *(float4*)&ug[rb] = make_float4(ua[r][0], ua[r][1], ua[r][2], ua[r][3]);
            *(float4*)&vg[rb] = make_float4(va[r][0], va[r][1], va[r][2], va[r][3]);
        }
    }
}

// ---------------- k_scene2: corr/thr + aggregations (no big LDS; L2-fed) ----------------

__global__ __launch_bounds__(TPB) void k_scene2(const float* __restrict__ out_ft,
                                                float* __restrict__ ws) {
    __shared__ float pd[256];
    __shared__ float dsm[121];
    __shared__ float corrv[121];
    __shared__ float red[4];
    __shared__ float sthr;
    const int t = threadIdx.x;
    const int scene = blockIdx.x;
    const int base = scene * 11;

    // dots: pair p = t>>1, half hf over d
    float part = 0.f;
    {
        int p = t >> 1, hf = t & 1;
        if (p < 121) {
            int i = p / 11, j = p - i * 11;
            const float* ra = out_ft + (size_t)(base + i) * 576 + hf * 128;
            const float* rb = out_ft + (size_t)(base + j) * 576 + hf * 128;
            #pragma unroll 8
            for (int dc = 0; dc < 32; ++dc) {
                float4 a = *(const float4*)&ra[dc*4];
                float4 b = *(const float4*)&rb[dc*4];
                part += a.x*b.x + a.y*b.y + a.z*b.z + a.w*b.w;
            }
        }
    }
    pd[t] = part;
    __syncthreads();
    if (t < 121) dsm[t] = pd[2*t] + pd[2*t+1];
    __syncthreads();
    if (t < 121) {
        int i = t / 11, j = t - i * 11;
        corrv[t] = dsm[t] * rsqrtf(dsm[i*11 + i] * dsm[j*11 + j]);
    }
    __syncthreads();
    float v = (t < 121) ? corrv[t] : 3.0e38f;
    for (int off = 32; off > 0; off >>= 1) v = fminf(v, __shfl_down(v, off));
    if ((t & 63) == 0) red[t >> 6] = v;
    __syncthreads();
    if (t == 0) {
        float a = fminf(fminf(red[0], red[1]), fminf(red[2], red[3]));
        sthr = (a < 0.4f) ? 0.4f : ((a > 0.4f && a < 0.6f) ? a + 0.1f : a + 0.03f);
    }
    __syncthreads();
    const float thr = sthr;

    // agg: col c, rows {ig, ig+4, ig+8}
    const int c = t & 63, ig = t >> 6;
    const int nr = (ig == 3) ? 2 : 3;
    float u1[3], u2[3], s1[3], s2[3], cnt[3];
    #pragma unroll
    for (int r = 0; r < 3; ++r) { s1[r] = 0.f; s2[r] = 0.f; cnt[r] = 0.f; }
    for (int r = 0; r < nr; ++r) {
        int row = ig + 4*r;
        u1[r] = ws[U1_O + (size_t)(base + row) * 64 + c];
        u2[r] = ws[U2_O + (size_t)(base + row) * 64 + c];
    }
    for (int j = 0; j < 11; ++j) {
        float v1 = ws[V1_O + (size_t)(base + j) * 64 + c];
        float v2 = ws[V2_O + (size_t)(base + j) * 64 + c];
        for (int r = 0; r < nr; ++r) {
            int row = ig + 4*r;
            float cw = corrv[row*11 + j];
            s1[r] += fmaxf(u1[r] + v1, 0.f);
            float adj = (cw >= thr) ? 1.f : 0.f;
            s2[r] += adj * fmaxf(u2[r] + v2, 0.f);
            cnt[r] += adj;
        }
    }
    for (int r = 0; r < nr; ++r) {
        int row = ig + 4*r;
        ws[U1_O + (size_t)(base + row) * 64 + c] = s1[r] * (1.f / 11.f);   // agg1
        ws[U2_O + (size_t)(base + row) * 64 + c] = s2[r] / (cnt[r] + 1e-6f); // agg2
    }
}

// ---------------- k_tail: inter = agg1@Wn1, feat = agg2@Wn2L ----------------

__global__ __launch_bounds__(TPB) void k_tail(const float* __restrict__ ws,
                                              const float* __restrict__ Wn1,
                                              float* __restrict__ out) {
    __shared__ float a1T[64*68];
    __shared__ float a2T[64*68];
    const int t = threadIdx.x;
    const int rowBase = blockIdx.x * 64;
    // stage agg transposed
    {
        int rr = t >> 2, cs = (t & 3) * 16;
        #pragma unroll
        for (int m = 0; m < 4; ++m) {
            float4 a = *(const float4*)&ws[U1_O + (size_t)(rowBase + rr) * 64 + cs + m*4];
            a1T[(cs+m*4+0)*68 + rr] = a.x; a1T[(cs+m*4+1)*68 + rr] = a.y;
            a1T[(cs+m*4+2)*68 + rr] = a.z; a1T[(cs+m*4+3)*68 + rr] = a.w;
            float4 b = *(const float4*)&ws[U2_O + (size_t)(rowBase + rr) * 64 + cs + m*4];
            a2T[(cs+m*4+0)*68 + rr] = b.x; a2T[(cs+m*4+1)*68 + rr] = b.y;
            a2T[(cs+m*4+2)*68 + rr] = b.z; a2T[(cs+m*4+3)*68 + rr] = b.w;
        }
    }
    __syncthreads();
    const int tg = t >> 4, tc = t & 15;
    const int r0 = tg * 4, c0 = tc * 4;

    // inter = agg1 @ Wn1 -> out[:,256:512]
    {
        float acc[4][16];
        #pragma unroll
        for (int r = 0; r < 4; ++r)
            #pragma unroll
            for (int c = 0; c < 16; ++c) acc[r][c] = 0.f;
        for (int k = 0; k < 64; ++k) {
            float4 av4 = *(const float4*)&a1T[k*68 + r0];
            float avr[4] = {av4.x, av4.y, av4.z, av4.w};
            float4 bv[4];
            #pragma unroll
            for (int j = 0; j < 4; ++j)
                bv[j] = *(const float4*)&Wn1[k*256 + tc*16 + j*4];
            #pragma unroll
            for (int r = 0; r < 4; ++r)
                #pragma unroll
                for (int j = 0; j < 4; ++j) {
                    acc[r][j*4+0] += avr[r] * bv[j].x;
                    acc[r][j*4+1] += avr[r] * bv[j].y;
                    acc[r][j*4+2] += avr[r] * bv[j].z;
                    acc[r][j*4+3] += avr[r] * bv[j].w;
                }
        }
        #pragma unroll
        for (int r = 0; r < 4; ++r) {
            size_t ob = (size_t)(rowBase + r0 + r) * 576 + 256 + tc*16;
            #pragma unroll
            for (int j = 0; j < 4; ++j)
                *(float4*)&out[ob + j*4] = make_float4(acc[r][j*4+0], acc[r][j*4+1],
                                                       acc[r][j*4+2], acc[r][j*4+3]);
        }
    }
    // feat = agg2 @ Wn2L -> out[:,512:576]
    {
        float fa[4][4];
        #pragma unroll
        for (int r = 0; r < 4; ++r)
            #pragma unroll
            for (int c = 0; c < 4; ++c) fa[r][c] = 0.f;
        for (int k = 0; k < 64; ++k) {
            float4 av4 = *(const float4*)&a2T[k*68 + r0];
            float avr[4] = {av4.x, av4.y, av4.z, av4.w};
            float4 bv = *(const float4*)&ws[WN2L_O + k*64 + c0];
            #pragma unroll
            for (int r = 0; r < 4; ++r) {
                fa[r][0] += avr[r] * bv.x; fa[r][1] += avr[r] * bv.y;
                fa[r][2] += avr[r] * bv.z; fa[r][3] += avr[r] * bv.w;
            }
        }
        #pragma unroll
        for (int r = 0; r < 4; ++r)
            *(float4*)&out[(size_t)(rowBase + r0 + r) * 576 + 512 + c0] =
                make_float4(fa[r][0], fa[r][1], fa[r][2], fa[r][3]);
    }
}

extern "C" void kernel_launch(void* const* d_in, const int* in_sizes, int n_in,
                              void* d_out, int out_size, void* d_ws, size_t ws_size,
                              hipStream_t stream) {
    (void)in_sizes; (void)n_in; (void)out_size; (void)ws_size;
    const float* in     = (const float*)d_in[0];
    const float* W_in   = (const float*)d_in[1];
    const float* b_in   = (const float*)d_in[2];
    const float* W_pos  = (const float*)d_in[3];
    const float* b_pos  = (const float*)d_in[4];
    const float* W_fc2  = (const float*)d_in[5];
    const float* b_fc2  = (const float*)d_in[6];
    const float* W_fc3  = (const float*)d_in[7];
    const float* b_fc3  = (const float*)d_in[8];
    const float* Wh1    = (const float*)d_in[9];
    const float* We1    = (const float*)d_in[10];
    const float* Wn1    = (const float*)d_in[11];
    const float* Wh2    = (const float*)d_in[12];
    const float* We2    = (const float*)d_in[13];
    const float* Wn2    = (const float*)d_in[14];
    const float* W_line = (const float*)d_in[15];
    float* out = (float*)d_out;
    float* ws  = (float*)d_ws;

    k_pre1<<<12, TPB, 0, stream>>>(W_in, b_in, W_pos, b_pos, ws);
    k_pre2<<<33, TPB, 0, stream>>>(W_fc2, b_fc2, ws);
    k_pre3<<<59, TPB, 0, stream>>>(W_fc3, b_fc3, Wn2, W_line, ws);
    k_pre4<<<22, TPB, 0, stream>>>(Wh1, Wh2, ws);
    k_rows<<<R_/64, TPB, 0, stream>>>(in, We1, We2, ws, out);
    k_scene2<<<B_, TPB, 0, stream>>>(out, ws);
    k_tail<<<R_/64, TPB, 0, stream>>>(ws, Wn1, out);
}

// Round 3
// 177.638 us; speedup vs baseline: 2.3229x; 2.3229x over previous
//
#include <hip/hip_runtime.h>

#define TPB 256

// Problem dims
constexpr int B_ = 4096, A_ = 11;
constexpr int R_ = B_ * A_;       // 45056 rows
constexpr int K32 = 32;           // L*IN folded input dim

// ws offsets (floats). Pre-region fits in [0, 32768); MH2/BH2 alias dead WC/XBASE/PE.
constexpr int M_O     = 0;        // 8192   folded through fc2 (32x256)
constexpr int M2_O    = 8192;     // 8192   folded through fc3 (32x256)
constexpr int WC_O    = 16384;    // 1024   W_in @ W_pos_top       [dead after preC]
constexpr int XBASE_O = 17408;    // 256    bpos + b_in@Wpos_top   [dead after preB]
constexpr int PE_O    = 17664;    // 2048   pe table               [dead after preB]
constexpr int XB_O    = 19712;    // 2048   per-timestep bias      [dead after preC]
constexpr int CB_O    = 21760;    // 256
constexpr int B2_O    = 22016;    // 2816   per-agent bias (11x256)
constexpr int WN2L_O  = 24832;    // 4096   Wn2 @ W_line (64x64)
constexpr int MH1_O   = 28928;    // 2048   M2 @ Wh1 (32x64)
constexpr int BH1_O   = 30976;    // 704
constexpr int MH2_O   = 16384;    // 2048   (aliases WC+XBASE, both dead)
constexpr int BH2_O   = 18432;    // 704    (aliases PE, dead)
constexpr int U1_O    = 32768;
constexpr int SZ_RH   = R_ * 64;  // 2883584
constexpr int V1_O    = U1_O + SZ_RH;
constexpr int U2_O    = V1_O + SZ_RH;
constexpr int V2_O    = U2_O + SZ_RH;

// ================= pre kernels: wide split-K folds =================
// pattern: 256 threads = 32 outputs x 8 K-splits, LDS reduce.

__global__ __launch_bounds__(TPB) void k_preA(const float* __restrict__ Win,
                                              const float* __restrict__ bin,
                                              const float* __restrict__ Wpos,
                                              const float* __restrict__ bpos,
                                              float* __restrict__ ws) {
    __shared__ float red[8 * 33];
    const int t = threadIdx.x, o8 = t & 31, ks = t >> 5;
    const int bx = blockIdx.x;
    if (bx < 32) {                       // Wc[i][j], 1024 outs, K=256
        int o = bx * 32 + o8, i = o >> 8, j = o & 255;
        const float* Ar = Win + i * 256;
        float p = 0.f;
        #pragma unroll 8
        for (int d = ks * 32; d < ks * 32 + 32; ++d) p += Ar[d] * Wpos[d * 256 + j];
        red[ks * 33 + o8] = p;
        __syncthreads();
        if (t < 32) {
            float s = 0.f;
            #pragma unroll
            for (int m = 0; m < 8; ++m) s += red[m * 33 + t];
            ws[WC_O + bx * 32 + t] = s;
        }
    } else if (bx < 40) {                // xbase[j] = bpos[j] + sum_d bin[d]*Wpos[d][j]
        int j = (bx - 32) * 32 + o8;
        float p = 0.f;
        #pragma unroll 8
        for (int d = ks * 32; d < ks * 32 + 32; ++d) p += bin[d] * Wpos[d * 256 + j];
        red[ks * 33 + o8] = p;
        __syncthreads();
        if (t < 32) {
            float s = bpos[(bx - 32) * 32 + t];
            #pragma unroll
            for (int m = 0; m < 8; ++m) s += red[m * 33 + t];
            ws[XBASE_O + (bx - 32) * 32 + t] = s;
        }
    } else {                             // pe table, 2048 outs, direct
        int o = (bx - 40) * 256 + t;
        int l = o >> 8, dd = o & 255;
        const float c0 = -logf(10000.f) / 256.f;
        float freq = expf((float)(dd & ~1) * c0);
        float ang = (float)l * freq;
        ws[PE_O + o] = (dd & 1) ? cosf(ang) : sinf(ang);
    }
}

__global__ __launch_bounds__(TPB) void k_preB(const float* __restrict__ Wpos,
                                              float* __restrict__ ws) {
    // xb[l][j] = xbase[j] + sum_d pe[l][d]*Wpos[256+d][j], 2048 outs, K=256
    __shared__ float red[8 * 33];
    const int t = threadIdx.x, o8 = t & 31, ks = t >> 5;
    int o = blockIdx.x * 32 + o8, l = o >> 8, j = o & 255;
    const float* per = ws + PE_O + l * 256;
    float p = 0.f;
    #pragma unroll 8
    for (int d = ks * 32; d < ks * 32 + 32; ++d) p += per[d] * Wpos[(256 + d) * 256 + j];
    red[ks * 33 + o8] = p;
    __syncthreads();
    if (t < 32) {
        int oo = blockIdx.x * 32 + t;
        float s = ws[XBASE_O + (oo & 255)];
        #pragma unroll
        for (int m = 0; m < 8; ++m) s += red[m * 33 + t];
        ws[XB_O + oo] = s;
    }
}

__global__ __launch_bounds__(TPB) void k_preC(const float* __restrict__ Wfc2,
                                              const float* __restrict__ bfc2,
                                              float* __restrict__ ws) {
    __shared__ float red[8 * 33];
    const int t = threadIdx.x, o8 = t & 31, ks = t >> 5;
    const int bx = blockIdx.x;
    if (bx < 256) {                      // M[k][j], 8192 outs, K=256; k=(l,i)
        int o = bx * 32 + o8, k = o >> 8, j = o & 255;
        int l = k >> 2, i = k & 3;
        const float* Ar = ws + WC_O + i * 256;
        const float* Br = Wfc2 + l * 65536 + j;
        float p = 0.f;
        #pragma unroll 8
        for (int d = ks * 32; d < ks * 32 + 32; ++d) p += Ar[d] * Br[d * 256];
        red[ks * 33 + o8] = p;
        __syncthreads();
        if (t < 32) {
            float s = 0.f;
            #pragma unroll
            for (int m = 0; m < 8; ++m) s += red[m * 33 + t];
            ws[M_O + bx * 32 + t] = s;
        }
    } else {                             // cb[j], 256 outs, K=2048 (l,d flattened)
        int j = (bx - 256) * 32 + o8;
        const float* Ar = ws + XB_O;
        float p = 0.f;
        #pragma unroll 4
        for (int dk = ks * 256; dk < ks * 256 + 256; ++dk) p += Ar[dk] * Wfc2[dk * 256 + j];
        red[ks * 33 + o8] = p;
        __syncthreads();
        if (t < 32) {
            int jj = (bx - 256) * 32 + t;
            float s = bfc2[jj];
            #pragma unroll
            for (int m = 0; m < 8; ++m) s += red[m * 33 + t];
            ws[CB_O + jj] = s;
        }
    }
}

__global__ __launch_bounds__(TPB) void k_preD(const float* __restrict__ Wfc3,
                                              const float* __restrict__ bfc3,
                                              const float* __restrict__ Wn2,
                                              const float* __restrict__ Wline,
                                              float* __restrict__ ws) {
    __shared__ float red[8 * 33];
    const int t = threadIdx.x, o8 = t & 31, ks = t >> 5;
    const int bx = blockIdx.x;
    if (bx < 256) {                      // M2 = M @ Wfc3_top, 8192 outs
        int o = bx * 32 + o8, k = o >> 8, j = o & 255;
        const float* Ar = ws + M_O + k * 256;
        float p = 0.f;
        #pragma unroll 8
        for (int d = ks * 32; d < ks * 32 + 32; ++d) p += Ar[d] * Wfc3[d * 256 + j];
        red[ks * 33 + o8] = p;
        __syncthreads();
        if (t < 32) {
            float s = 0.f;
            #pragma unroll
            for (int m = 0; m < 8; ++m) s += red[m * 33 + t];
            ws[M2_O + bx * 32 + t] = s;
        }
    } else if (bx < 344) {               // bias2[a][j], 2816 outs
        int o = (bx - 256) * 32 + o8, a = o >> 8, j = o & 255;
        const float* Ar = ws + CB_O;
        float p = 0.f;
        #pragma unroll 8
        for (int d = ks * 32; d < ks * 32 + 32; ++d) p += Ar[d] * Wfc3[d * 256 + j];
        red[ks * 33 + o8] = p;
        __syncthreads();
        if (t < 32) {
            int oo = (bx - 256) * 32 + t;
            int aa = oo >> 8, jj = oo & 255;
            float s = bfc3[jj] + Wfc3[(256 + aa) * 256 + jj];
            #pragma unroll
            for (int m = 0; m < 8; ++m) s += red[m * 33 + t];
            ws[B2_O + oo] = s;
        }
    } else {                             // Wn2L = Wn2 @ W_line, 4096 outs
        int o = (bx - 344) * 32 + o8, k = o >> 6, c = o & 63;
        const float* Ar = Wn2 + k * 256;
        float p = 0.f;
        #pragma unroll 8
        for (int d = ks * 32; d < ks * 32 + 32; ++d) p += Ar[d] * Wline[d * 64 + c];
        red[ks * 33 + o8] = p;
        __syncthreads();
        if (t < 32) {
            float s = 0.f;
            #pragma unroll
            for (int m = 0; m < 8; ++m) s += red[m * 33 + t];
            ws[WN2L_O + (bx - 344) * 32 + t] = s;
        }
    }
}

__global__ __launch_bounds__(TPB) void k_preE(const float* __restrict__ Wh1,
                                              const float* __restrict__ Wh2,
                                              float* __restrict__ ws) {
    __shared__ float red[8 * 33];
    const int t = threadIdx.x, o8 = t & 31, ks = t >> 5;
    const int bx = blockIdx.x;
    const float* Aw;  const float* Bw;  int oo_base;  int out_o;  int mode;
    if (bx < 64)       { mode = 0; out_o = MH1_O; oo_base = bx * 32;         Bw = Wh1; }
    else if (bx < 86)  { mode = 1; out_o = BH1_O; oo_base = (bx - 64) * 32;  Bw = Wh1; }
    else if (bx < 150) { mode = 0; out_o = MH2_O; oo_base = (bx - 86) * 32;  Bw = Wh2; }
    else               { mode = 1; out_o = BH2_O; oo_base = (bx - 150) * 32; Bw = Wh2; }
    int o = oo_base + o8;
    int r = o >> 6, c = o & 63;
    Aw = ws + (mode == 0 ? M2_O : B2_O) + r * 256;
    float p = 0.f;
    #pragma unroll 8
    for (int d = ks * 32; d < ks * 32 + 32; ++d) p += Aw[d] * Bw[d * 64 + c];
    red[ks * 33 + o8] = p;
    __syncthreads();
    if (t < 32) {
        float s = 0.f;
        #pragma unroll
        for (int m = 0; m < 8; ++m) s += red[m * 33 + t];
        ws[out_o + oo_base + t] = s;
    }
}

// ================= k_rows3: ftraj + h + u/v, LDS-B GEMM, 64 rows/block =================
// A reads: ds_read_b128 of row-chunks, broadcast within 16-lane phase (conflict-free).
// B staged in 16KB LDS halves. No transposes anywhere.

__global__ __launch_bounds__(TPB) void k_rows3(const float* __restrict__ in,
                                               const float* __restrict__ We1g,
                                               const float* __restrict__ We2g,
                                               float* __restrict__ ws,
                                               float* __restrict__ out) {
    __shared__ float inS[64 * 32];   // 8 KB, row-major
    __shared__ float hS[64 * 64];    // 16 KB, row-major
    __shared__ float Bs[4096];       // 16 KB staging
    const int t = threadIdx.x;
    const int rowBase = blockIdx.x * 64;
    const int tg = t >> 4, tc = t & 15;
    const int r0 = tg * 4;

    // stage input rows (coalesced float4)
    {
        const float4* src = (const float4*)(in + (size_t)rowBase * K32);
        float4* dst = (float4*)inS;
        dst[t] = src[t];
        dst[t + 256] = src[t + 256];
    }
    __syncthreads();

    int ag[4];
    #pragma unroll
    for (int r = 0; r < 4; ++r) ag[r] = (rowBase + r0 + r) % 11;

    // ---- ftraj = in @ M2 + bias2 -> out[:,0:256]; thread tile 4r x 16c ----
    {
        float acc[4][16];
        #pragma unroll
        for (int r = 0; r < 4; ++r)
            #pragma unroll
            for (int c = 0; c < 16; ++c) acc[r][c] = 0.f;
        for (int kh = 0; kh < 2; ++kh) {
            if (kh) __syncthreads();
            {   // stage M2 rows kh*16..+16 (16KB)
                const float4* src = (const float4*)(ws + M2_O + kh * 4096);
                float4* dst = (float4*)Bs;
                #pragma unroll
                for (int m = 0; m < 4; ++m) dst[t + m * 256] = src[t + m * 256];
            }
            __syncthreads();
            #pragma unroll
            for (int kq = 0; kq < 4; ++kq) {
                float avq[4][4];
                #pragma unroll
                for (int r = 0; r < 4; ++r) {
                    float4 a4 = *(const float4*)&inS[(r0 + r) * 32 + kh * 16 + kq * 4];
                    avq[r][0] = a4.x; avq[r][1] = a4.y; avq[r][2] = a4.z; avq[r][3] = a4.w;
                }
                #pragma unroll
                for (int kk = 0; kk < 4; ++kk) {
                    float4 b[4];
                    #pragma unroll
                    for (int j = 0; j < 4; ++j)
                        b[j] = *(const float4*)&Bs[(kq * 4 + kk) * 256 + tc * 16 + j * 4];
                    #pragma unroll
                    for (int r = 0; r < 4; ++r) {
                        float a = avq[r][kk];
                        #pragma unroll
                        for (int j = 0; j < 4; ++j) {
                            acc[r][j * 4 + 0] += a * b[j].x;
                            acc[r][j * 4 + 1] += a * b[j].y;
                            acc[r][j * 4 + 2] += a * b[j].z;
                            acc[r][j * 4 + 3] += a * b[j].w;
                        }
                    }
                }
            }
        }
        #pragma unroll
        for (int r = 0; r < 4; ++r) {
            size_t ob = (size_t)(rowBase + r0 + r) * 576 + tc * 16;
            const float* bb = ws + B2_O + ag[r] * 256 + tc * 16;
            #pragma unroll
            for (int j = 0; j < 4; ++j) {
                float4 b = *(const float4*)&bb[j * 4];
                *(float4*)&out[ob + j * 4] =
                    make_float4(acc[r][j * 4 + 0] + b.x, acc[r][j * 4 + 1] + b.y,
                                acc[r][j * 4 + 2] + b.z, acc[r][j * 4 + 3] + b.w);
            }
        }
    }

    // ---- two NMP stages; h-tile 4r x 4c (c0 = tc*4) ----
    const int c0 = tc * 4;
    for (int s = 0; s < 2; ++s) {
        const int mh_o = s ? MH2_O : MH1_O;
        const int bh_o = s ? BH2_O : BH1_O;
        const float* We = s ? We2g : We1g;
        float* ug = ws + (s ? U2_O : U1_O);
        float* vg = ws + (s ? V2_O : V1_O);

        __syncthreads();
        {   // stage Mh_s (8KB) into Bs[0..2047]
            const float4* src = (const float4*)(ws + mh_o);
            float4* dst = (float4*)Bs;
            dst[t] = src[t];
            if (t < 256) dst[t + 256] = src[t + 256];
        }
        __syncthreads();
        // h = relu(in @ Mh + bh)
        float hacc[4][4];
        #pragma unroll
        for (int r = 0; r < 4; ++r)
            #pragma unroll
            for (int c = 0; c < 4; ++c) hacc[r][c] = 0.f;
        #pragma unroll
        for (int kq = 0; kq < 8; ++kq) {
            float avq[4][4];
            #pragma unroll
            for (int r = 0; r < 4; ++r) {
                float4 a4 = *(const float4*)&inS[(r0 + r) * 32 + kq * 4];
                avq[r][0] = a4.x; avq[r][1] = a4.y; avq[r][2] = a4.z; avq[r][3] = a4.w;
            }
            #pragma unroll
            for (int kk = 0; kk < 4; ++kk) {
                float4 b = *(const float4*)&Bs[(kq * 4 + kk) * 64 + c0];
                #pragma unroll
                for (int r = 0; r < 4; ++r) {
                    float a = avq[r][kk];
                    hacc[r][0] += a * b.x; hacc[r][1] += a * b.y;
                    hacc[r][2] += a * b.z; hacc[r][3] += a * b.w;
                }
            }
        }
        #pragma unroll
        for (int r = 0; r < 4; ++r) {
            float4 b = *(const float4*)&ws[bh_o + ag[r] * 64 + c0];
            float4 h = make_float4(fmaxf(hacc[r][0] + b.x, 0.f), fmaxf(hacc[r][1] + b.y, 0.f),
                                   fmaxf(hacc[r][2] + b.z, 0.f), fmaxf(hacc[r][3] + b.w, 0.f));
            *(float4*)&hS[(r0 + r) * 64 + c0] = h;
        }
        __syncthreads();   // hS ready; Mh reads done

        // u = h @ We[0:64], v = h @ We[64:128]
        float ua[4][4], va[4][4];
        #pragma unroll
        for (int r = 0; r < 4; ++r)
            #pragma unroll
            for (int c = 0; c < 4; ++c) { ua[r][c] = 0.f; va[r][c] = 0.f; }
        for (int kh = 0; kh < 2; ++kh) {
            if (kh) __syncthreads();
            {   // stage We rows [kh*32..+32) and [64+kh*32..+32)  (16KB)
                const float4* s0 = (const float4*)(We + kh * 2048);
                const float4* s1 = (const float4*)(We + 4096 + kh * 2048);
                float4* dst = (float4*)Bs;
                dst[t] = s0[t];
                if (t < 256) dst[t + 256] = s0[t + 256];
                dst[t + 512] = s1[t];
                if (t < 256) dst[t + 768] = s1[t + 256];
            }
            __syncthreads();
            #pragma unroll
            for (int kq = 0; kq < 8; ++kq) {
                float avq[4][4];
                #pragma unroll
                for (int r = 0; r < 4; ++r) {
                    float4 a4 = *(const float4*)&hS[(r0 + r) * 64 + kh * 32 + kq * 4];
                    avq[r][0] = a4.x; avq[r][1] = a4.y; avq[r][2] = a4.z; avq[r][3] = a4.w;
                }
                #pragma unroll
                for (int kk = 0; kk < 4; ++kk) {
                    float4 bu = *(const float4*)&Bs[(kq * 4 + kk) * 64 + c0];
                    float4 bv = *(const float4*)&Bs[2048 + (kq * 4 + kk) * 64 + c0];
                    #pragma unroll
                    for (int r = 0; r < 4; ++r) {
                        float a = avq[r][kk];
                        ua[r][0] += a * bu.x; ua[r][1] += a * bu.y;
                        ua[r][2] += a * bu.z; ua[r][3] += a * bu.w;
                        va[r][0] += a * bv.x; va[r][1] += a * bv.y;
                        va[r][2] += a * bv.z; va[r][3] += a * bv.w;
                    }
                }
            }
        }
        #pragma unroll
        for (int r = 0; r < 4; ++r) {
            size_t rb = (size_t)(rowBase + r0 + r) * 64 + c0;
            *(float4*)&ug[rb] = make_float4(ua[r][0], ua[r][1], ua[r][2], ua[r][3]);
            *(float4*)&vg[rb] = make_float4(va[r][0], va[r][1], va[r][2], va[r][3]);
        }
    }
}

// ================= k_scene3: corr/thr + agg + tail GEMMs, fully fused =================

__global__ __launch_bounds__(TPB) void k_scene3(const float* __restrict__ out_ft,
                                                const float* __restrict__ Wn1,
                                                float* __restrict__ ws,
                                                float* __restrict__ out) {
    __shared__ float ftS[11 * 260];
    __shared__ float u1s[704], v1s[704], u2s[704], v2s[704];
    __shared__ float dots[121];
    __shared__ float corrv[121];
    __shared__ float red[4];
    __shared__ float sthr;
    const int t = threadIdx.x;
    const int scene = blockIdx.x;
    const int base = scene * 11;

    // stage ftraj rows + u/v (coalesced float4)
    for (int o = t; o < 704; o += TPB) {
        int row = o >> 6, c4 = o & 63;
        ((float4*)ftS)[row * 65 + c4] =
            *(const float4*)&out_ft[(size_t)(base + row) * 576 + c4 * 4];
    }
    {
        const float4* su1 = (const float4*)(ws + U1_O + (size_t)base * 64);
        const float4* sv1 = (const float4*)(ws + V1_O + (size_t)base * 64);
        const float4* su2 = (const float4*)(ws + U2_O + (size_t)base * 64);
        const float4* sv2 = (const float4*)(ws + V2_O + (size_t)base * 64);
        if (t < 176) {
            ((float4*)u1s)[t] = su1[t];
            ((float4*)v1s)[t] = sv1[t];
            ((float4*)u2s)[t] = su2[t];
            ((float4*)v2s)[t] = sv2[t];
        }
    }
    __syncthreads();

    // dots
    if (t < 121) {
        int i = t / 11, j = t - i * 11;
        float s = 0.f;
        #pragma unroll 8
        for (int kq = 0; kq < 64; ++kq) {
            float4 a = *(const float4*)&ftS[i * 260 + kq * 4];
            float4 b = *(const float4*)&ftS[j * 260 + kq * 4];
            s += a.x * b.x + a.y * b.y + a.z * b.z + a.w * b.w;
        }
        dots[t] = s;
    }
    __syncthreads();
    if (t < 121) {
        int i = t / 11, j = t - i * 11;
        corrv[t] = dots[t] * rsqrtf(dots[i * 11 + i] * dots[j * 11 + j]);
    }
    __syncthreads();
    float v = (t < 121) ? corrv[t] : 3.0e38f;
    for (int off = 32; off > 0; off >>= 1) v = fminf(v, __shfl_down(v, off));
    if ((t & 63) == 0) red[t >> 6] = v;
    __syncthreads();
    if (t == 0) {
        float a = fminf(fminf(red[0], red[1]), fminf(red[2], red[3]));
        sthr = (a < 0.4f) ? 0.4f : ((a > 0.4f && a < 0.6f) ? a + 0.1f : a + 0.03f);
    }
    __syncthreads();
    const float thr = sthr;

    // agg: c = t&63, rows {g, g+4, g+8}; write agg in place over u-slots
    {
        const int c = t & 63, g = t >> 6;
        const int nr = (g == 3) ? 2 : 3;
        float u1[3], u2[3], s1[3], s2[3], cnt[3];
        #pragma unroll
        for (int r = 0; r < 3; ++r) { s1[r] = 0.f; s2[r] = 0.f; cnt[r] = 0.f; }
        for (int r = 0; r < nr; ++r) {
            u1[r] = u1s[(g + 4 * r) * 64 + c];
            u2[r] = u2s[(g + 4 * r) * 64 + c];
        }
        #pragma unroll
        for (int j = 0; j < 11; ++j) {
            float vv1 = v1s[j * 64 + c];
            float vv2 = v2s[j * 64 + c];
            for (int r = 0; r < nr; ++r) {
                float cw = corrv[(g + 4 * r) * 11 + j];
                s1[r] += fmaxf(u1[r] + vv1, 0.f);
                float adj = (cw >= thr) ? 1.f : 0.f;
                s2[r] += adj * fmaxf(u2[r] + vv2, 0.f);
                cnt[r] += adj;
            }
        }
        for (int r = 0; r < nr; ++r) {
            u1s[(g + 4 * r) * 64 + c] = s1[r] * (1.f / 11.f);     // agg1
            u2s[(g + 4 * r) * 64 + c] = s2[r] / (cnt[r] + 1e-6f); // agg2
        }
    }
    __syncthreads();

    // inter = agg1 @ Wn1 -> out[:,256:512]; one column per thread, B in regs
    {
        const int c = t;
        float breg[64];
        #pragma unroll
        for (int k = 0; k < 64; ++k) breg[k] = Wn1[k * 256 + c];
        float acc[11];
        #pragma unroll
        for (int i = 0; i < 11; ++i) acc[i] = 0.f;
        #pragma unroll
        for (int kq = 0; kq < 16; ++kq) {
            #pragma unroll
            for (int i = 0; i < 11; ++i) {
                float4 a = *(const float4*)&u1s[i * 64 + kq * 4];
                acc[i] += a.x * breg[kq * 4 + 0] + a.y * breg[kq * 4 + 1]
                        + a.z * breg[kq * 4 + 2] + a.w * breg[kq * 4 + 3];
            }
        }
        #pragma unroll
        for (int i = 0; i < 11; ++i)
            out[(size_t)(base + i) * 576 + 256 + c] = acc[i];
    }
    // feat = agg2 @ Wn2L -> out[:,512:576]
    {
        const int c = t & 63, g = t >> 6;
        const int nr = (g == 3) ? 2 : 3;
        float wreg[64];
        #pragma unroll
        for (int k = 0; k < 64; ++k) wreg[k] = ws[WN2L_O + k * 64 + c];
        float acc[3] = {0.f, 0.f, 0.f};
        #pragma unroll
        for (int kq = 0; kq < 16; ++kq) {
            for (int r = 0; r < nr; ++r) {
                float4 a = *(const float4*)&u2s[(g + 4 * r) * 64 + kq * 4];
                acc[r] += a.x * wreg[kq * 4 + 0] + a.y * wreg[kq * 4 + 1]
                        + a.z * wreg[kq * 4 + 2] + a.w * wreg[kq * 4 + 3];
            }
        }
        for (int r = 0; r < nr; ++r)
            out[(size_t)(base + g + 4 * r) * 576 + 512 + c] = acc[r];
    }
}

extern "C" void kernel_launch(void* const* d_in, const int* in_sizes, int n_in,
                              void* d_out, int out_size, void* d_ws, size_t ws_size,
                              hipStream_t stream) {
    (void)in_sizes; (void)n_in; (void)out_size; (void)ws_size;
    const float* in     = (const float*)d_in[0];
    const float* W_in   = (const float*)d_in[1];
    const float* b_in   = (const float*)d_in[2];
    const float* W_pos  = (const float*)d_in[3];
    const float* b_pos  = (const float*)d_in[4];
    const float* W_fc2  = (const float*)d_in[5];
    const float* b_fc2  = (const float*)d_in[6];
    const float* W_fc3  = (const float*)d_in[7];
    const float* b_fc3  = (const float*)d_in[8];
    const float* Wh1    = (const float*)d_in[9];
    const float* We1    = (const float*)d_in[10];
    const float* Wn1    = (const float*)d_in[11];
    const float* Wh2    = (const float*)d_in[12];
    const float* We2    = (const float*)d_in[13];
    const float* Wn2    = (const float*)d_in[14];
    const float* W_line = (const float*)d_in[15];
    float* out = (float*)d_out;
    float* ws  = (float*)d_ws;

    k_preA<<<48, TPB, 0, stream>>>(W_in, b_in, W_pos, b_pos, ws);
    k_preB<<<64, TPB, 0, stream>>>(W_pos, ws);
    k_preC<<<264, TPB, 0, stream>>>(W_fc2, b_fc2, ws);
    k_preD<<<472, TPB, 0, stream>>>(W_fc3, b_fc3, Wn2, W_line, ws);
    k_preE<<<172, TPB, 0, stream>>>(Wh1, Wh2, ws);
    k_rows3<<<R_ / 64, TPB, 0, stream>>>(in, We1, We2, ws, out);
    k_scene3<<<B_, TPB, 0, stream>>>(out, Wn1, ws, out);
}